// Round 5
// baseline (184.554 us; speedup 1.0000x reference)
//
#include <hip/hip_runtime.h>
#include <hip/hip_bf16.h>
#include <stdint.h>

#define N_PTS   8192
#define D       256
#define N_E     8192
#define BETA    0.25f
#define EPS_1   1.0000001f   // 1 + 1e-7 (rounds to 1+ulp in f32, same as jnp)

typedef unsigned long long u64;
typedef __attribute__((ext_vector_type(8))) short bf16x8;   // 8 bf16 = 4 VGPR
typedef __attribute__((ext_vector_type(8))) short short8;
typedef __attribute__((ext_vector_type(4))) float f32x4;

// ---- workspace layout (bytes) ----
// Fragment-linear bf16 arrays: element (p,k) of an 8192x256 matrix lives at
//   blk = (p>>4)*8 + (k>>5);  l = ((k>>3)&3)*16 + (p&15);  j = k&7
//   idx = blk*512 + l*8 + j
// Each 16x32 MFMA fragment is a contiguous 1KB block in lane-major order:
// global_load_lds(uniform base + lane*16) and ds_read_b128(lane*16) are both
// perfectly linear -> zero bank conflicts (verified rounds 3-4: conflicts = 0).
#define WS_KEYS   0
#define WS_COUNTS (N_PTS * 8)                    // 64 KB
#define WS_LOSS   (WS_COUNTS + N_E * 4)          // +32 KB
#define WS_AHI    (1 << 20)                      // 1 MB-aligned
#define WS_ALO    (WS_AHI + N_PTS * D * 2)
#define WS_BHI    (WS_ALO + N_PTS * D * 2)
#define WS_BLO    (WS_BHI + N_E * D * 2)         // total ~17 MB

__device__ __forceinline__ short f2bf(float x) {
    __hip_bfloat16 h = __float2bfloat16(x);      // RTN-even
    return *reinterpret_cast<short*>(&h);
}
__device__ __forceinline__ float bf2f(short s) {
    __hip_bfloat16 h = *reinterpret_cast<__hip_bfloat16*>(&s);
    return __bfloat162float(h);
}

#define GLOAD16(gp, lp) __builtin_amdgcn_global_load_lds(                      \
    (const __attribute__((address_space(1))) void*)(gp),                       \
    (__attribute__((address_space(3))) void*)(lp), 16, 0, 0)

// ------- init + split f32 -> bf16 hi/lo, fragment-linear layout -------------
__global__ __launch_bounds__(256) void k_prep(
    const float* __restrict__ u, const float* __restrict__ cb,
    short* __restrict__ Ahi, short* __restrict__ Alo,
    short* __restrict__ Bhi, short* __restrict__ Blo,
    u64* __restrict__ keys, float* __restrict__ counts,
    double* __restrict__ loss_sum)
{
    const int tid = blockIdx.x * 256 + threadIdx.x;   // 0 .. 262143
    if (tid < N_E)   counts[tid] = 0.f;
    if (tid < N_PTS) keys[tid] = ~0ULL;
    if (tid == 0)    *loss_sum = 0.0;

    const int blk = tid >> 6;            // = (p>>4)*8 + (k>>5)
    const int l   = tid & 63;
    const int s   = blk >> 3, c = blk & 7;
    const int p   = s * 16 + (l & 15);
    const int k   = c * 32 + (l >> 4) * 8;
    const size_t gin  = (size_t)p * D + k;
    const size_t gout = (size_t)tid * 8;

    float v[8];
    short8 h8, l8;

    *(float4*)&v[0] = *(const float4*)&u[gin];
    *(float4*)&v[4] = *(const float4*)&u[gin + 4];
    if (k == 0) v[0] = -v[0];            // Minkowski sign fold on time comp
    #pragma unroll
    for (int j = 0; j < 8; ++j) {
        h8[j] = f2bf(v[j]);
        l8[j] = f2bf(v[j] - bf2f(h8[j]));
    }
    *(short8*)&Ahi[gout] = h8;
    *(short8*)&Alo[gout] = l8;

    *(float4*)&v[0] = *(const float4*)&cb[gin];
    *(float4*)&v[4] = *(const float4*)&cb[gin + 4];
    #pragma unroll
    for (int j = 0; j < 8; ++j) {
        h8[j] = f2bf(v[j]);
        l8[j] = f2bf(v[j] - bf2f(h8[j]));
    }
    *(short8*)&Bhi[gout] = h8;
    *(short8*)&Blo[gout] = l8;
}

// ---------------- MFMA argmin: C = A~ . B^T, per-row argmin, no C write ------
// split-bf16: a.b = ahi.bhi + ahi.blo + alo.bhi  (err ~2^-18 rel, safe margin)
// 256x256 tile, 8 waves (2M x 4N), BK=32, double-buffered LDS, phase-split
// pipeline (T3+T4): prefetch issued a full K-tile ahead; __syncthreads drains
// it AFTER ~4 phases of MFMA have covered the latency. T5 setprio on clusters.
#define BMM 256
#define BNN 256
#define NKS 8                // K-steps of 32

__global__ __launch_bounds__(512, 2) void k_argmin_mfma(
    const short* __restrict__ Ahi, const short* __restrict__ Alo,
    const short* __restrict__ Bhi, const short* __restrict__ Blo,
    u64* __restrict__ keys)
{
    __shared__ short sm[2][4][16 * 512];  // [dbuf][Ahi,Alo,Bhi,Blo][16 KB] = 128 KB

    const int t    = threadIdx.x;
    const int w    = t >> 6;              // wave 0..7
    const int l    = t & 63;
    // natural order (round-4 verified locality: FETCH 37 MB): rb-major
    const int rb   = blockIdx.x >> 5;     // 32 row-panels (points)
    const int cbk  = blockIdx.x & 31;     // 32 col-panels (codes)
    const int r0   = rb * BMM, c0 = cbk * BNN;
    const int wr   = w >> 2, wc = w & 3;  // 2x4 wave grid, 128x64 each

    // staging role: array a = w&3, half = w>>2 (8 fragment-blocks each)
    const int a    = w & 3;
    const int half = w >> 2;
    const short* gsrc = (a == 0) ? Ahi : (a == 1) ? Alo : (a == 2) ? Bhi : Blo;
    const int ab   = ((a < 2) ? rb : cbk) * 16 + half * 8;  // first slice

    f32x4 acc[8][4];
    #pragma unroll
    for (int i = 0; i < 8; ++i)
        #pragma unroll
        for (int j = 0; j < 4; ++j) acc[i][j] = (f32x4){0.f, 0.f, 0.f, 0.f};

    // prologue: stage K-tile 0 into buf 0
    #pragma unroll
    for (int i = 0; i < 8; ++i)
        GLOAD16(gsrc + ((size_t)(ab + i) * 8 + 0) * 512 + l * 8,
                &sm[0][a][(half * 8 + i) * 512]);

    for (int kk = 0; kk < NKS; ++kk) {
        const int c = kk & 1;
        // drains vmcnt(0)+lgkmcnt(0)+barrier: tile kk staged by ALL waves;
        // also proves all waves finished reading buf c^1 (prev iter MFMAs).
        __syncthreads();

        // prefetch next K-tile into buf c^1 (in flight across all 4 phases)
        if (kk < NKS - 1) {
            #pragma unroll
            for (int i = 0; i < 8; ++i)
                GLOAD16(gsrc + ((size_t)(ab + i) * 8 + kk + 1) * 512 + l * 8,
                        &sm[c ^ 1][a][(half * 8 + i) * 512]);
        }

        bf16x8 bh[4], bl[4];
        #pragma unroll
        for (int nf = 0; nf < 4; ++nf) {
            bh[nf] = *(const bf16x8*)&sm[c][2][(wc * 4 + nf) * 512 + l * 8];
            bl[nf] = *(const bf16x8*)&sm[c][3][(wc * 4 + nf) * 512 + l * 8];
        }
        #pragma unroll
        for (int ph = 0; ph < 4; ++ph) {
            bf16x8 ah[2], al[2];
            #pragma unroll
            for (int q = 0; q < 2; ++q) {
                const int mf = ph * 2 + q;
                ah[q] = *(const bf16x8*)&sm[c][0][(wr * 8 + mf) * 512 + l * 8];
                al[q] = *(const bf16x8*)&sm[c][1][(wr * 8 + mf) * 512 + l * 8];
            }
            __builtin_amdgcn_s_setprio(1);
            #pragma unroll
            for (int q = 0; q < 2; ++q) {
                const int mf = ph * 2 + q;
                #pragma unroll
                for (int nf = 0; nf < 4; ++nf) {
                    acc[mf][nf] = __builtin_amdgcn_mfma_f32_16x16x32_bf16(
                        ah[q], bh[nf], acc[mf][nf], 0, 0, 0);
                    acc[mf][nf] = __builtin_amdgcn_mfma_f32_16x16x32_bf16(
                        ah[q], bl[nf], acc[mf][nf], 0, 0, 0);
                    acc[mf][nf] = __builtin_amdgcn_mfma_f32_16x16x32_bf16(
                        al[q], bh[nf], acc[mf][nf], 0, 0, 0);
                }
            }
            __builtin_amdgcn_s_setprio(0);
            if (ph < 3) __builtin_amdgcn_s_barrier();  // phase lockstep
        }
    }

    // epilogue: per-row argmin over this block's 256 codes, then atomicMin
    // C/D layout (m89-verified): col = lane&15, row = (lane>>4)*4 + reg
    const int g  = l >> 4;
    const int cc = l & 15;
    #pragma unroll
    for (int mf = 0; mf < 8; ++mf) {
        #pragma unroll
        for (int r = 0; r < 4; ++r) {
            u64 km = ~0ULL;
            #pragma unroll
            for (int nf = 0; nf < 4; ++nf) {
                float m = fmaxf(-acc[mf][nf][r], EPS_1);   // m >= 1 > 0
                unsigned code = (unsigned)(c0 + wc * 64 + nf * 16 + cc);
                u64 key = ((u64)__float_as_uint(m) << 32) | code;
                km = key < km ? key : km;
            }
            #pragma unroll
            for (int s = 8; s >= 1; s >>= 1) {             // 16-lane col groups
                u64 o = __shfl_xor(km, s);
                km = o < km ? o : km;
            }
            if (cc == 0)
                atomicMin(&keys[r0 + wr * 128 + mf * 16 + g * 4 + r], km);
        }
    }
}

// ---------------- gather z_q, per-pair f32 distance, histogram ----------------
__global__ __launch_bounds__(256) void k_gather(
    const float* __restrict__ u, const float* __restrict__ cb,
    const u64* __restrict__ keys, float* __restrict__ out,
    float* __restrict__ counts, double* __restrict__ loss_sum)
{
    __shared__ float sred[4];
    const int t    = threadIdx.x;
    const int w    = t >> 6;
    const int row  = blockIdx.x * 4 + w;
    const int lane = t & 63;
    const u64 key  = keys[row];
    const int idx  = (int)(unsigned)(key & 0xffffffffULL);

    float* zq = out + 1;
    float4 uv = *(const float4*)&u[(size_t)row * D + lane * 4];
    float4 cv = *(const float4*)&cb[(size_t)idx * D + lane * 4];
    if (lane == 0) uv.x = -uv.x;                  // Lorentzian sign
    float partial = uv.x * cv.x + uv.y * cv.y + uv.z * cv.z + uv.w * cv.w;
    *(float4*)&zq[(size_t)row * D + lane * 4] = cv;

    #pragma unroll
    for (int s = 32; s >= 1; s >>= 1)
        partial += __shfl_xor(partial, s);

    if (lane == 0) {
        float m = fmaxf(-partial, EPS_1);
        sred[w] = acoshf(m);
        atomicAdd(&counts[idx], 1.f);             // scattered: low contention
    }
    __syncthreads();
    if (t == 0)                                   // 1 f64 atomic per block
        atomicAdd(loss_sum, (double)(sred[0] + sred[1] + sred[2] + sred[3]));
}

// ---------------- scalars: loss, perplexity, entropy, e_mean -----------------
__global__ __launch_bounds__(256) void k_final(
    const float* __restrict__ counts, const double* __restrict__ loss_sum,
    float* __restrict__ out)
{
    __shared__ float red[256];
    const int t = threadIdx.x;
    const int OFF_P = 1 + N_PTS * D;
    float ent = 0.f;
    for (int i = t; i < N_E; i += 256) {
        float e = counts[i] * (1.0f / N_PTS);
        out[OFF_P + 2 + i] = e;
        ent -= e * logf(e + 1e-10f);
    }
    red[t] = ent;
    __syncthreads();
    for (int s = 128; s > 0; s >>= 1) {
        if (t < s) red[t] += red[t + s];
        __syncthreads();
    }
    if (t == 0) {
        float entropy = red[0];
        out[0]         = (1.0f + BETA) * (float)(*loss_sum / (double)N_PTS);
        out[OFF_P]     = expf(entropy);
        out[OFF_P + 1] = entropy;
    }
}

// ---------------- launch ----------------
extern "C" void kernel_launch(void* const* d_in, const int* in_sizes, int n_in,
                              void* d_out, int out_size, void* d_ws, size_t ws_size,
                              hipStream_t stream)
{
    const float* u  = (const float*)d_in[0];
    const float* cb = (const float*)d_in[1];
    float* out = (float*)d_out;
    char* ws = (char*)d_ws;

    u64*    keys     = (u64*)(ws + WS_KEYS);
    float*  counts   = (float*)(ws + WS_COUNTS);
    double* loss_sum = (double*)(ws + WS_LOSS);
    short*  Ahi = (short*)(ws + WS_AHI);
    short*  Alo = (short*)(ws + WS_ALO);
    short*  Bhi = (short*)(ws + WS_BHI);
    short*  Blo = (short*)(ws + WS_BLO);

    k_prep<<<N_PTS * D / 8 / 256, 256, 0, stream>>>(u, cb, Ahi, Alo, Bhi, Blo,
                                                    keys, counts, loss_sum);
    k_argmin_mfma<<<(N_PTS / BMM) * (N_E / BNN), 512, 0, stream>>>(
        Ahi, Alo, Bhi, Blo, keys);
    k_gather<<<N_PTS / 4, 256, 0, stream>>>(u, cb, keys, out, counts, loss_sum);
    k_final<<<1, 256, 0, stream>>>(counts, loss_sum, out);
}